// Round 21
// baseline (51.400 us; speedup 1.0000x reference)
//
#include <hip/hip_runtime.h>
#include <math.h>

#define M_  2
#define B_  256
#define L_  1024
#define K_  4
#define S_  20
#define NR_ 100
#define NTERM 7   // Taylor terms T_1..T_7 ; ||mu*Q||inf <= 0.13 -> rem ~2e-11

typedef float f32x4_t __attribute__((ext_vector_type(4)));
typedef _Float16 f16;
typedef f16 f16x8 __attribute__((ext_vector_type(8)));
typedef f16 f16x4 __attribute__((ext_vector_type(4)));

__device__ __forceinline__ float softplusf(float x) {
    return x > 20.0f ? x : log1pf(expf(x));
}

// ---------------------------------------------------------------------------
// Kernel 1: per (m,k), compute normalized Q, store T_n = Q^n/n!, n=1..NTERM.
// 8 blocks (serial chain lives here only; R16: never fuse the r-loop here).
// ---------------------------------------------------------------------------
__global__ __launch_bounds__(512)
void qpow_kernel(const float* __restrict__ exch,   // (M,K,S,S)
                 const float* __restrict__ equil,  // (M,K,S)
                 float*       __restrict__ Qpow)   // (M,K,NTERM,400)
{
    __shared__ float sQ[400];
    __shared__ float sT[2][400];
    __shared__ float sRow[20];

    const int blk = blockIdx.x;          // mm*K_ + kk
    const int kk = blk % K_;
    const int mm = blk / K_;
    const int tid = threadIdx.x;
    const bool act = tid < 400;
    const int i = tid / 20;
    const int j = tid - i * 20;

    float p[20];
    float Q0 = 0.0f, rowsum = 0.0f;

    if (act) {
        const float* eq = equil + (mm * K_ + kk) * S_;
        float mx = eq[0];
        #pragma unroll
        for (int z = 1; z < 20; ++z) mx = fmaxf(mx, eq[z]);
        float s = 0.0f;
        #pragma unroll
        for (int z = 0; z < 20; ++z) { p[z] = expf(eq[z] - mx); s += p[z]; }
        const float inv = 1.0f / s;
        #pragma unroll
        for (int z = 0; z < 20; ++z) p[z] *= inv;

        const float* Kx = exch + (mm * K_ + kk) * S_ * S_;
        float R = (i == j) ? 0.0f : softplusf(0.5f * (Kx[i * 20 + j] + Kx[j * 20 + i]));
        Q0 = R * p[j];
        sQ[tid] = Q0;
    }
    __syncthreads();

    if (act) {
        rowsum = 0.0f;
        #pragma unroll
        for (int z = 0; z < 20; ++z) rowsum += sQ[i * 20 + z];
        if (j == 0) sRow[i] = rowsum;
    }
    __syncthreads();

    float* Tout = Qpow + (size_t)blk * (NTERM * 400);
    if (act) {
        float mue = 0.0f;
        #pragma unroll
        for (int z = 0; z < 20; ++z) mue += p[z] * sRow[z];
        float q = (Q0 - ((i == j) ? rowsum : 0.0f)) / fmaxf(mue, 1e-16f);
        sQ[tid] = q;
        sT[0][tid] = q;
        Tout[tid] = q;       // T_1 = Q
    }
    __syncthreads();

    int cur = 0;
    for (int n = 2; n <= NTERM; ++n) {
        if (act) {
            float acc = 0.0f;
            #pragma unroll
            for (int z = 0; z < 20; ++z) acc += sT[cur][i * 20 + z] * sQ[z * 20 + j];
            acc /= (float)n;
            sT[cur ^ 1][tid] = acc;
            Tout[(n - 1) * 400 + tid] = acc;   // T_n = Q^n / n!
        }
        __syncthreads();
        cur ^= 1;
    }
}

// ---------------------------------------------------------------------------
// Kernel 2: P[m,r,k] = I + sum_n mu^n T_n  (linear combo, no matmuls).
// 800 blocks -- wide and parallel (the fused 8-block producer costs ~52us).
// ---------------------------------------------------------------------------
__global__ __launch_bounds__(512)
void pbuild_kernel(const float* __restrict__ Qpow,  // (M,K,NTERM,400)
                   const float* __restrict__ tauk,  // (M,NR)
                   const float* __restrict__ pmrk,  // (M,K)
                   float*       __restrict__ Pws)   // (M,NR,K,400)
{
    const int blk = blockIdx.x;          // mm*NR*K + rr*K + kk
    const int kk = blk % K_;
    const int rr = (blk / K_) % NR_;
    const int mm = blk / (K_ * NR_);
    const int tid = threadIdx.x;
    if (tid >= 400) return;

    const float mu = softplusf(tauk[mm * NR_ + rr]) * softplusf(pmrk[mm * K_ + kk]);
    const float* T = Qpow + ((size_t)(mm * K_ + kk) * NTERM) * 400 + tid;

    float acc = (tid % 21 == 0) ? 1.0f : 0.0f;   // identity
    float mp = mu;
    #pragma unroll
    for (int n = 0; n < NTERM; ++n) { acc = fmaf(mp, T[n * 400], acc); mp *= mu; }
    Pws[(size_t)blk * 400 + tid] = acc;
}

// ---------------------------------------------------------------------------
// Kernel 3 (MFMA einsum, R20 champion + R18's DMA staging):
// A staged as f32 via global_load_lds (linear 20 KB, no VGPR round-trip,
// no f16 conversion pass, no ds_writes); f32->f16 conversion happens at
// fragment-load time per K-group (kg=lane>>4: 8/8/4/0 floats; kg2-3 cover
// the K=20->32 zero-pad). P staged transposed f16 as before (small).
// D = P^T A^T per 16x16 tile; lane stores one f32x4 (4 contiguous cols of
// an output row) THROUGH L2. 2048 blocks x 256 threads; one barrier.
// ---------------------------------------------------------------------------
#define TPB3 256

__device__ __forceinline__ void dma16(const void* gsrc, void* lds_base) {
    __builtin_amdgcn_global_load_lds(
        (const __attribute__((address_space(1))) void*)gsrc,
        (__attribute__((address_space(3))) void*)lds_base,
        16, 0, 0);
}

__global__ __launch_bounds__(TPB3)
void einsum_kernel(const float* __restrict__ inp,  // (M,B,L,S)
                   const float* __restrict__ Pws,  // (M,NR,K,400)
                   const int*   __restrict__ ridx, // (M,B)
                   float*       __restrict__ out)  // (M,B,L,K*S)
{
    __shared__ __align__(16) float A32[256 * 20];   // 20480 B, [row l][z] f32
    __shared__ __align__(16) f16 P_ldsT[80 * 40];   //  6400 B, [n][z] pad40

    const int bx      = blockIdx.x;
    const int quarter = bx & 3;            // L_/256 = 4
    const int mb      = bx >> 2;           // 0..511
    const int mm      = mb >> 8;
    const int tid     = threadIdx.x;
    const int wave    = tid >> 6;
    const int lane    = tid & 63;

    const int r = ridx[mb];                // block-uniform
    const size_t row0 = (size_t)mb * L_ + (size_t)quarter * 256;

    // ---- stage A via DMA: 20 KB = 20 x 1KB wave-chunks; 4 waves x 5 ----
    {
        const char* gin = (const char*)(inp + row0 * 20);
        char* la = (char*)A32;
        #pragma unroll
        for (int q = 0; q < 5; ++q) {
            const int off = (q * 4 + wave) * 1024;
            dma16(gin + off + lane * 16, la + off);
        }
    }

    // ---- stage P transposed: P_ldsT[n=kk*20+s][z] = P[z][s] of matrix kk ----
    {
        const float* Psrc = Pws + ((size_t)(mm * NR_ + r) * K_) * 400;
        for (int idx = tid; idx < 1600; idx += TPB3) {
            const int n  = idx / 20;
            const int z  = idx - n * 20;
            const int kk = n / 20;
            const int s  = n - kk * 20;
            P_ldsT[n * 40 + z] = (f16)Psrc[kk * 400 + z * 20 + s];
        }
        if (tid < 80) {
            const f16x4 z4 = {(f16)0, (f16)0, (f16)0, (f16)0};
            *(f16x4*)&P_ldsT[tid * 40 + 20] = z4;
            *(f16x4*)&P_ldsT[tid * 40 + 24] = z4;
            *(f16x4*)&P_ldsT[tid * 40 + 28] = z4;
        }
    }
    __syncthreads();                       // drains DMA vmcnt + lgkm; the ONLY barrier

    const int lrow = lane & 15;            // frag row/col within tile
    const int kg   = lane >> 4;            // K-group 0..3
    const int lk   = kg * 8;               // K offset
    const int crow = kg * 4;               // D row base (= output col base)

    // A-operand fragments: P^T rows n = nt*16+lrow, k-contiguous (f16 LDS)
    f16x8 Pf[5];
    #pragma unroll
    for (int nt = 0; nt < 5; ++nt)
        Pf[nt] = *(const f16x8*)&P_ldsT[(nt * 16 + lrow) * 40 + lk];

    const f32x4_t cz = {0.f, 0.f, 0.f, 0.f};

    #pragma unroll
    for (int tm = 0; tm < 4; ++tm) {
        const int tile = wave * 4 + tm;    // 0..15 M-tiles
        // B-operand fragment from f32 LDS, converted per K-group:
        // kg0: z0-7, kg1: z8-15, kg2: z16-19 + 4 zeros, kg3: all zeros
        const float* arow = A32 + (tile * 16 + lrow) * 20;
        f16x8 Af;
        if (kg < 2) {
            const f32x4_t a = *(const f32x4_t*)(arow + lk);
            const f32x4_t b = *(const f32x4_t*)(arow + lk + 4);
            Af = (f16x8){ (f16)a.x, (f16)a.y, (f16)a.z, (f16)a.w,
                          (f16)b.x, (f16)b.y, (f16)b.z, (f16)b.w };
        } else if (kg == 2) {
            const f32x4_t a = *(const f32x4_t*)(arow + 16);
            Af = (f16x8){ (f16)a.x, (f16)a.y, (f16)a.z, (f16)a.w,
                          (f16)0, (f16)0, (f16)0, (f16)0 };
        } else {
            Af = (f16x8){ (f16)0, (f16)0, (f16)0, (f16)0,
                          (f16)0, (f16)0, (f16)0, (f16)0 };
        }

        float* orow = out + (row0 + tile * 16 + lrow) * 80;
        #pragma unroll
        for (int nt = 0; nt < 5; ++nt) {
            f32x4_t c = __builtin_amdgcn_mfma_f32_16x16x32_f16(Pf[nt], Af, cz, 0, 0, 0);
            *(f32x4_t*)(orow + nt * 16 + crow) = c;   // through L2 (write-combine)
        }
    }
}

// ---------------------------------------------------------------------------
extern "C" void kernel_launch(void* const* d_in, const int* in_sizes, int n_in,
                              void* d_out, int out_size, void* d_ws, size_t ws_size,
                              hipStream_t stream) {
    const float* inp   = (const float*)d_in[0];  // (M,B,L,S)
    const float* tauk  = (const float*)d_in[1];  // (M,NR)
    const float* exch  = (const float*)d_in[2];  // (M,K,S,S)
    const float* equil = (const float*)d_in[3];  // (M,K,S)
    const float* pmrk  = (const float*)d_in[4];  // (M,K)
    const int*   ridx  = (const int*)d_in[5];    // (M,B)
    float* outp = (float*)d_out;

    float* Qpow = (float*)d_ws;                          // 89.6 KB
    float* Pws  = Qpow + (size_t)M_ * K_ * NTERM * 400;  // 1.28 MB

    qpow_kernel<<<M_ * K_, 512, 0, stream>>>(exch, equil, Qpow);
    pbuild_kernel<<<M_ * NR_ * K_, 512, 0, stream>>>(Qpow, tauk, pmrk, Pws);
    einsum_kernel<<<M_ * B_ * 4, TPB3, 0, stream>>>(inp, Pws, ridx, outp);
}